// Round 5
// baseline (122.988 us; speedup 1.0000x reference)
//
#include <hip/hip_runtime.h>
#include <math.h>

#define NS 29

__device__ __forceinline__ float4 qmul4(float4 a, float4 b) {
    return make_float4(
        a.w*b.x + a.x*b.w + a.y*b.z - a.z*b.y,
        a.w*b.y - a.x*b.z + a.y*b.w + a.z*b.x,
        a.w*b.z + a.x*b.y - a.y*b.x + a.z*b.w,
        a.w*b.w - a.x*b.x - a.y*b.y - a.z*b.z);
}

// rotate v=(0,1,0) by q_inv(q) = (-x,-y,-z,w), reference q_rot formula
__device__ __forceinline__ void qinv_rot_up(float4 q, float out[3]) {
    float qx = -q.x, qy = -q.y, qz = -q.z, qw = q.w;
    float tx = -2.f*qz;
    float ty = 0.f;
    float tz = 2.f*qx;
    out[0] = 0.f + qw*tx + (qy*tz - qz*ty);
    out[1] = 1.f + qw*ty + (qz*tx - qx*tz);
    out[2] = 0.f + qw*tz + (qx*ty - qy*tx);
}

__device__ __forceinline__ float wave_sum(float v) {
    v += __shfl_xor(v, 32);
    v += __shfl_xor(v, 16);
    v += __shfl_xor(v, 8);
    v += __shfl_xor(v, 4);
    v += __shfl_xor(v, 2);
    v += __shfl_xor(v, 1);
    return v;
}

__device__ __forceinline__ int wave_sum_i(int v) {
    v += __shfl_xor(v, 32);
    v += __shfl_xor(v, 16);
    v += __shfl_xor(v, 8);
    v += __shfl_xor(v, 4);
    v += __shfl_xor(v, 2);
    v += __shfl_xor(v, 1);
    return v;
}

__device__ void jacobi3f(float A[3][3], float V[3][3]) {
    V[0][0]=1.f; V[0][1]=0.f; V[0][2]=0.f;
    V[1][0]=0.f; V[1][1]=1.f; V[1][2]=0.f;
    V[2][0]=0.f; V[2][1]=0.f; V[2][2]=1.f;
    for (int sweep = 0; sweep < 6; ++sweep) {
        float off = A[0][1]*A[0][1] + A[0][2]*A[0][2] + A[1][2]*A[1][2];
        float dia = A[0][0]*A[0][0] + A[1][1]*A[1][1] + A[2][2]*A[2][2];
        if (off <= 1e-12f * (dia + 1e-30f)) break;
        for (int p = 0; p < 2; ++p) for (int q = p + 1; q < 3; ++q) {
            float apq = A[p][q];
            if (fabsf(apq) < 1e-30f) continue;
            float theta = (A[q][q] - A[p][p]) / (2.0f * apq);
            float t = ((theta >= 0.f) ? 1.f : -1.f) / (fabsf(theta) + sqrtf(theta*theta + 1.f));
            float cc = 1.f / sqrtf(t*t + 1.f);
            float ss = t * cc;
            float app = A[p][p], aqq = A[q][q];
            A[p][p] = app - t * apq;
            A[q][q] = aqq + t * apq;
            A[p][q] = 0.f; A[q][p] = 0.f;
            int r = 3 - p - q;
            float arp = A[r][p], arq = A[r][q];
            A[r][p] = cc*arp - ss*arq; A[p][r] = A[r][p];
            A[r][q] = ss*arp + cc*arq; A[q][r] = A[r][q];
            for (int i = 0; i < 3; ++i) {
                float vip = V[i][p], viq = V[i][q];
                V[i][p] = cc*vip - ss*viq;
                V[i][q] = ss*vip + cc*viq;
            }
        }
    }
}

__device__ void mat2quatf(const float R[3][3], float q[4]) {
    const float eps = 1e-12f;
    float tr = R[0][0] + R[1][1] + R[2][2];
    if (tr > 0.f) {
        float S = sqrtf(fmaxf(tr + 1.f, eps)) * 2.f;
        q[0] = (R[2][1]-R[1][2])/S; q[1] = (R[0][2]-R[2][0])/S;
        q[2] = (R[1][0]-R[0][1])/S; q[3] = 0.25f*S;
    } else if ((R[0][0] > R[1][1]) && (R[0][0] > R[2][2])) {
        float S = sqrtf(fmaxf(1.f + R[0][0] - R[1][1] - R[2][2], eps)) * 2.f;
        q[0] = 0.25f*S; q[1] = (R[0][1]+R[1][0])/S;
        q[2] = (R[0][2]+R[2][0])/S; q[3] = (R[2][1]-R[1][2])/S;
    } else if (R[1][1] > R[2][2]) {
        float S = sqrtf(fmaxf(1.f + R[1][1] - R[0][0] - R[2][2], eps)) * 2.f;
        q[0] = (R[0][1]+R[1][0])/S; q[1] = 0.25f*S;
        q[2] = (R[1][2]+R[2][1])/S; q[3] = (R[0][2]-R[2][0])/S;
    } else {
        float S = sqrtf(fmaxf(1.f + R[2][2] - R[0][0] - R[1][1], eps)) * 2.f;
        q[0] = (R[0][2]+R[2][0])/S; q[1] = (R[1][2]+R[2][1])/S;
        q[2] = 0.25f*S; q[3] = (R[1][0]-R[0][1])/S;
    }
}

// ---------------- kernel 1 (fused): scan + stats + per-wave solve --------------
// One wave per segment (round-0 geometry — empirically fastest inner loop:
// lane-stride-1 coalesced loads, depth-2 software pipeline). Three merges:
// (a) starts[e] computed per-wave from the 16KB L1/L2-resident counts array
//     (coalesced stride-64 loop + int butterfly) -> scan kernel+launch removed;
// (b) after the stats butterfly every lane holds the full 29 segment sums, so
//     the solve (round-1-verified code) runs per-wave, redundant across lanes;
// (c) 5 losses stored as ONE 32B row per segment -> NO atomics here (round-1
//     lesson: 20K same-line atomics serialize at one TCC channel, ~40us).
// pass1's speed itself is floor-bound by dirty-L3 evictions from the harness's
// 268MB poison fill (rounds 0/3/4 invariance) — not worth further layout work.
// acc layout: 0-2 sum_p, 3-5 sum_g, 6 sum|p|^2, 7 sum|g|^2, 8-16 H_raw,
// 17-26 M upper tri, 27 sum(1-cos_grav), 28 sum(1-dot_deg^2) [ci<4]
__global__ __launch_bounds__(256) void fused_kernel(
    const float* __restrict__ pred_t, const float4* __restrict__ pred_q,
    const float* __restrict__ gt_t,   const float4* __restrict__ gt_q,
    const int* __restrict__ counts,
    float* __restrict__ Lbuf, float* __restrict__ out, int E)
{
    int wv = threadIdx.x >> 6;
    int lane = threadIdx.x & 63;
    // zero the 5 output accumulators before reduce_kernel's atomics (stream-
    // ordered: all fused blocks retire before reduce starts)
    if (blockIdx.x == 0 && threadIdx.x < 5) out[threadIdx.x] = 0.0f;
    int e = blockIdx.x * 4 + wv;
    if (e >= E) return;                 // no barriers in this kernel: safe
    int ci = counts[e];

    // ---- merged scan: start = sum counts[0..e), wave-uniform ----
    // counts is 16KB -> L1/L2-resident after first touch; coalesced loads.
    int part = 0;
    for (int k = lane; k < e; k += 64) part += counts[k];
    int start = wave_sum_i(part);

    bool small_c = (ci < 4);
    float4 q0p = pred_q[start];
    float4 q0g = gt_q[start];
    float4 q0pi = make_float4(-q0p.x, -q0p.y, -q0p.z, q0p.w);
    float4 q0gi = make_float4(-q0g.x, -q0g.y, -q0g.z, q0g.w);

    float acc[NS];
    #pragma unroll
    for (int k = 0; k < NS; ++k) acc[k] = 0.f;

    int iters = (ci + 63) >> 6;
    int i = lane;
    // prologue: load slot 0 (clamped index; counts >= 2 always)
    int m = start + min(i, ci - 1);
    float px = pred_t[3*m+0], py = pred_t[3*m+1], pz = pred_t[3*m+2];
    float gx = gt_t[3*m+0],  gy = gt_t[3*m+1],  gz = gt_t[3*m+2];
    float4 pq = pred_q[m];
    float4 gq = gt_q[m];

    for (int j = 0; ; ) {
        // ---- prefetch next slot before consuming current ----
        float npx = 0.f, npy = 0.f, npz = 0.f, ngx = 0.f, ngy = 0.f, ngz = 0.f;
        float4 npq = make_float4(0.f,0.f,0.f,0.f), ngq = npq;
        bool have_next = (j + 1 < iters);
        if (have_next) {
            int m2 = start + min(i + 64, ci - 1);
            npx = pred_t[3*m2+0]; npy = pred_t[3*m2+1]; npz = pred_t[3*m2+2];
            ngx = gt_t[3*m2+0];  ngy = gt_t[3*m2+1];  ngz = gt_t[3*m2+2];
            npq = pred_q[m2];
            ngq = gt_q[m2];
        }
        // ---- accumulate current (predicated on validity) ----
        if (i < ci) {
            acc[0] += px; acc[1] += py; acc[2] += pz;
            acc[3] += gx; acc[4] += gy; acc[5] += gz;
            acc[6] += px*px + py*py + pz*pz;
            acc[7] += gx*gx + gy*gy + gz*gz;
            acc[8]  += px*gx; acc[9]  += px*gy; acc[10] += px*gz;
            acc[11] += py*gx; acc[12] += py*gy; acc[13] += py*gz;
            acc[14] += pz*gx; acc[15] += pz*gy; acc[16] += pz*gz;

            // m_i = d(dot)/d(q_align_i), dot = <q_mul(q_align, pq), gq>
            float mx =  pq.w*gq.x - pq.z*gq.y + pq.y*gq.z - pq.x*gq.w;
            float my =  pq.z*gq.x + pq.w*gq.y - pq.x*gq.z - pq.y*gq.w;
            float mz = -pq.y*gq.x + pq.x*gq.y + pq.w*gq.z - pq.z*gq.w;
            float mw =  pq.x*gq.x + pq.y*gq.y + pq.z*gq.z + pq.w*gq.w;
            acc[17] += mx*mx; acc[18] += mx*my; acc[19] += mx*mz; acc[20] += mx*mw;
            acc[21] += my*my; acc[22] += my*mz; acc[23] += my*mw;
            acc[24] += mz*mz; acc[25] += mz*mw; acc[26] += mw*mw;

            // gravity: unit quats -> |pu|=|gu|=1, skip norm/div (R5-verified)
            float pu[3], gu[3];
            qinv_rot_up(pq, pu);
            qinv_rot_up(gq, gu);
            float cosv = pu[0]*gu[0] + pu[1]*gu[1] + pu[2]*gu[2];
            acc[27] += 1.f - cosv;

            if (small_c) {
                float4 aa = qmul4(q0pi, pq);
                float4 bb = qmul4(q0gi, gq);
                float dd = aa.x*bb.x + aa.y*bb.y + aa.z*bb.z + aa.w*bb.w;
                acc[28] += 1.f - dd*dd;
            }
        }
        if (!have_next) break;
        px = npx; py = npy; pz = npz;
        gx = ngx; gy = ngy; gz = ngz;
        pq = npq; gq = ngq;
        i += 64; ++j;
    }

    // butterfly reduce: afterwards EVERY lane holds the full segment sums
    #pragma unroll
    for (int k = 0; k < NS; ++k) acc[k] = wave_sum(acc[k]);

    // ---------------- fused solve (wave-uniform, all lanes redundant) ---------
    // (verbatim round-1-verified code; absmax was 0.0 there)
    float c = (float)ci;
    float mu_p[3] = { acc[0]/c, acc[1]/c, acc[2]/c };
    float mu_g[3] = { acc[3]/c, acc[4]/c, acc[5]/c };
    float pp_c = acc[6] - c*(mu_p[0]*mu_p[0]+mu_p[1]*mu_p[1]+mu_p[2]*mu_p[2]);
    float gg_c = acc[7] - c*(mu_g[0]*mu_g[0]+mu_g[1]*mu_g[1]+mu_g[2]*mu_g[2]);
    float H[3][3];
    H[0][0]=acc[8] -c*mu_p[0]*mu_g[0]; H[0][1]=acc[9] -c*mu_p[0]*mu_g[1]; H[0][2]=acc[10]-c*mu_p[0]*mu_g[2];
    H[1][0]=acc[11]-c*mu_p[1]*mu_g[0]; H[1][1]=acc[12]-c*mu_p[1]*mu_g[1]; H[1][2]=acc[13]-c*mu_p[1]*mu_g[2];
    H[2][0]=acc[14]-c*mu_p[2]*mu_g[0]; H[2][1]=acc[15]-c*mu_p[2]*mu_g[1]; H[2][2]=acc[16]-c*mu_p[2]*mu_g[2];
    float g_var = gg_c / (c - 1.0f);
    bool deg = small_c || (g_var < 1e-4f);
    float trans, rot, scale = 0.f;
    if (deg) {
        float s28;
        if (small_c) {
            s28 = acc[28];
        } else {
            // data-degenerate large segment (essentially never): re-stream,
            // lane-parallel
            float local = 0.f;
            for (int ii = lane; ii < ci; ii += 64) {
                float4 aa = qmul4(q0pi, pred_q[start + ii]);
                float4 bb = qmul4(q0gi, gt_q[start + ii]);
                float dd = aa.x*bb.x + aa.y*bb.y + aa.z*bb.z + aa.w*bb.w;
                local += 1.f - dd*dd;
            }
            s28 = wave_sum(local);
        }
        float trH = H[0][0] + H[1][1] + H[2][2];
        trans = (pp_c - 2.f*trH + gg_c) / (c * 3.f);
        rot = s28 / c;
    } else {
        float B[3][3], V[3][3];
        for (int ii = 0; ii < 3; ++ii)
            for (int jj = 0; jj < 3; ++jj)
                B[ii][jj] = H[0][ii]*H[0][jj] + H[1][ii]*H[1][jj] + H[2][ii]*H[2][jj];
        jacobi3f(B, V);
        float lam[3] = { B[0][0], B[1][1], B[2][2] };
        int idx[3] = {0, 1, 2};
        if (lam[idx[0]] < lam[idx[1]]) { int t = idx[0]; idx[0] = idx[1]; idx[1] = t; }
        if (lam[idx[0]] < lam[idx[2]]) { int t = idx[0]; idx[0] = idx[2]; idx[2] = t; }
        if (lam[idx[1]] < lam[idx[2]]) { int t = idx[1]; idx[1] = idx[2]; idx[2] = t; }
        float v1[3], v2[3], v3[3];
        for (int ii = 0; ii < 3; ++ii) { v1[ii] = V[ii][idx[0]]; v2[ii] = V[ii][idx[1]]; v3[ii] = V[ii][idx[2]]; }
        float detV = v1[0]*(v2[1]*v3[2]-v2[2]*v3[1])
                   - v1[1]*(v2[0]*v3[2]-v2[2]*v3[0])
                   + v1[2]*(v2[0]*v3[1]-v2[1]*v3[0]);
        float sgnV = (detV < 0.f) ? -1.f : 1.f;
        float u1[3], u2[3], u3[3];
        for (int ii = 0; ii < 3; ++ii) u1[ii] = H[ii][0]*v1[0] + H[ii][1]*v1[1] + H[ii][2]*v1[2];
        float n1 = fmaxf(sqrtf(u1[0]*u1[0]+u1[1]*u1[1]+u1[2]*u1[2]), 1e-30f);
        for (int ii = 0; ii < 3; ++ii) u1[ii] /= n1;
        for (int ii = 0; ii < 3; ++ii) u2[ii] = H[ii][0]*v2[0] + H[ii][1]*v2[1] + H[ii][2]*v2[2];
        float d12 = u1[0]*u2[0]+u1[1]*u2[1]+u1[2]*u2[2];
        for (int ii = 0; ii < 3; ++ii) u2[ii] -= d12*u1[ii];
        float n2 = fmaxf(sqrtf(u2[0]*u2[0]+u2[1]*u2[1]+u2[2]*u2[2]), 1e-30f);
        for (int ii = 0; ii < 3; ++ii) u2[ii] /= n2;
        u3[0] = u1[1]*u2[2] - u1[2]*u2[1];
        u3[1] = u1[2]*u2[0] - u1[0]*u2[2];
        u3[2] = u1[0]*u2[1] - u1[1]*u2[0];
        // R = v1 u1^T + v2 u2^T + sgnV*v3 u3^T (== ref V diag(1,1,sgn) U^T)
        float R[3][3];
        for (int ii = 0; ii < 3; ++ii)
            for (int kk = 0; kk < 3; ++kk)
                R[ii][kk] = v1[ii]*u1[kk] + v2[ii]*u2[kk] + sgnV*v3[ii]*u3[kk];
        float nom = 0.f;
        for (int kk = 0; kk < 3; ++kk)
            for (int jj = 0; jj < 3; ++jj)
                nom += R[kk][jj] * H[jj][kk];
        float denom = pp_c;
        float s = 1.f;
        if (denom > 1e-6f) {
            s = nom / fmaxf(denom, 1e-6f);
            s = fminf(fmaxf(s, 1e-3f), 1e3f);
        }
        trans = (s*s*denom - 2.f*s*nom + gg_c) / (c * 3.f);
        float ls = logf(fabsf(s) + 1e-6f);
        scale = ls * ls;
        float q[4];
        mat2quatf(R, q);
        float quad = q[0]*q[0]*acc[17] + q[1]*q[1]*acc[21] + q[2]*q[2]*acc[24] + q[3]*q[3]*acc[26]
            + 2.f*(q[0]*q[1]*acc[18] + q[0]*q[2]*acc[19] + q[0]*q[3]*acc[20]
                 + q[1]*q[2]*acc[22] + q[1]*q[3]*acc[23] + q[2]*q[3]*acc[25]);
        rot = (c - quad) / c;
    }
    float grav = acc[27] / c;
    // leash: pred_t[start] (uniform broadcast load)
    float tx = pred_t[3*start+0], ty = pred_t[3*start+1], tz = pred_t[3*start+2];
    float mag = sqrtf(tx*tx + ty*ty + tz*tz);
    float ml = fmaxf(mag - 15.f, 0.f);
    float Ed = (float)E;

    // one coalesced 32B row per segment; lanes 5-7 pad with zeros
    float outv = 0.f;
    if (lane == 0) outv = trans / Ed;
    else if (lane == 1) outv = rot / Ed;
    else if (lane == 2) outv = grav / Ed;
    else if (lane == 3) outv = (ml * ml) / Ed;
    else if (lane == 4) outv = scale / Ed;
    if (lane < 8)
        Lbuf[(size_t)e * 8 + lane] = outv;
}

// ---------------- kernel 2: tiny loss reduction --------------------------------
// 4096 rows x 32B (L2/L3-warm, written by fused_kernel). 64 blocks x 64
// threads; wave-reduce then 5 atomics per block = 320 total (the measured-safe
// count; round-1 lesson: never scale same-line atomics with E).
__global__ __launch_bounds__(64) void reduce_kernel(
    const float* __restrict__ Lbuf, float* __restrict__ out, int E)
{
    int e = blockIdx.x * 64 + threadIdx.x;
    float v[5] = {0.f, 0.f, 0.f, 0.f, 0.f};
    if (e < E) {
        const float4* r = (const float4*)(Lbuf + (size_t)e * 8);
        float4 a = r[0];
        float4 b = r[1];
        v[0] = a.x; v[1] = a.y; v[2] = a.z; v[3] = a.w; v[4] = b.x;
    }
    #pragma unroll
    for (int k = 0; k < 5; ++k) {
        float s = wave_sum(v[k]);
        if (threadIdx.x == 0) atomicAdd(out + k, s);
    }
}

extern "C" void kernel_launch(void* const* d_in, const int* in_sizes, int n_in,
                              void* d_out, int out_size, void* d_ws, size_t ws_size,
                              hipStream_t stream) {
    const float*  pred_t = (const float*)d_in[0];
    const float4* pred_q = (const float4*)d_in[1];
    const float*  gt_t   = (const float*)d_in[2];
    const float4* gt_q   = (const float4*)d_in[3];
    const int*    counts = (const int*)d_in[4];
    int E = in_sizes[4];

    float* Lbuf = (float*)d_ws;   // E x 8 floats of per-segment losses

    fused_kernel<<<(E + 3) / 4, 256, 0, stream>>>(pred_t, pred_q, gt_t, gt_q,
                                                  counts, Lbuf, (float*)d_out, E);
    reduce_kernel<<<(E + 63) / 64, 64, 0, stream>>>(Lbuf, (float*)d_out, E);
}

// Round 6
// 118.462 us; speedup vs baseline: 1.0382x; 1.0382x over previous
//
#include <hip/hip_runtime.h>
#include <math.h>

// ---------------- kernel 1: shfl-based exclusive scan + zero d_out -------------
// (round-3-verified shfl scan: 3 barriers vs 20; absmax 0.0 in rounds 3-5)
__global__ void scan_kernel(const int* __restrict__ counts,
                            int* __restrict__ starts,
                            float* __restrict__ out, int E) {
    __shared__ int wtot[16];
    int tid = threadIdx.x;
    int lane = tid & 63, wv = tid >> 6;
    if (tid < 5) out[tid] = 0.0f;
    int base = tid * 4;
    int c0 = (base + 0 < E) ? counts[base + 0] : 0;
    int c1 = (base + 1 < E) ? counts[base + 1] : 0;
    int c2 = (base + 2 < E) ? counts[base + 2] : 0;
    int c3 = (base + 3 < E) ? counts[base + 3] : 0;
    int s = c0 + c1 + c2 + c3;
    int incl = s;
    #pragma unroll
    for (int d = 1; d < 64; d <<= 1) {
        int t = __shfl_up(incl, d);
        if (lane >= d) incl += t;
    }
    if (lane == 63) wtot[wv] = incl;
    __syncthreads();
    if (wv == 0) {
        int v = (lane < 16) ? wtot[lane] : 0;
        int iv = v;
        #pragma unroll
        for (int d = 1; d < 16; d <<= 1) {
            int t = __shfl_up(iv, d);
            if (lane >= d) iv += t;
        }
        if (lane < 16) wtot[lane] = iv - v;   // exclusive wave offsets
    }
    __syncthreads();
    int excl = wtot[wv] + (incl - s);
    if (base + 0 < E) starts[base + 0] = excl; excl += c0;
    if (base + 1 < E) starts[base + 1] = excl; excl += c1;
    if (base + 2 < E) starts[base + 2] = excl; excl += c2;
    if (base + 3 < E) starts[base + 3] = excl;
}

__device__ __forceinline__ float4 qmul4(float4 a, float4 b) {
    return make_float4(
        a.w*b.x + a.x*b.w + a.y*b.z - a.z*b.y,
        a.w*b.y - a.x*b.z + a.y*b.w + a.z*b.x,
        a.w*b.z + a.x*b.y - a.y*b.x + a.z*b.w,
        a.w*b.w - a.x*b.x - a.y*b.y - a.z*b.z);
}

// rotate v=(0,1,0) by q_inv(q) = (-x,-y,-z,w), reference q_rot formula
__device__ __forceinline__ void qinv_rot_up(float4 q, float out[3]) {
    float qx = -q.x, qy = -q.y, qz = -q.z, qw = q.w;
    float tx = -2.f*qz;
    float ty = 0.f;
    float tz = 2.f*qx;
    out[0] = 0.f + qw*tx + (qy*tz - qz*ty);
    out[1] = 1.f + qw*ty + (qz*tx - qx*tz);
    out[2] = 0.f + qw*tz + (qx*ty - qy*tx);
}

__device__ __forceinline__ float wave_sum(float v) {
    v += __shfl_xor(v, 32);
    v += __shfl_xor(v, 16);
    v += __shfl_xor(v, 8);
    v += __shfl_xor(v, 4);
    v += __shfl_xor(v, 2);
    v += __shfl_xor(v, 1);
    return v;
}

// ---------------- kernel 2: per-segment sufficient statistics ------------------
// EXACT round-0 structure (session best, 118.576 us measured): 4 independent
// waves per 256-block, one segment per wave, NO barrier, lane-stride-1
// coalesced loads, depth-2 software pipeline (~112 B/lane in flight).
// Six configurations (rounds 0-5) bracketed this kernel's core at ~24 us
// invariant to layout/occupancy/pipelining — it is bound by the memory-system
// state inherited from the harness's 256 MiB poison fill, not by this code.
// stats row (32 floats): 0-2 sum_p, 3-5 sum_g, 6 sum|p|^2, 7 sum|g|^2,
// 8-16 H_raw, 17-26 M upper tri, 27 sum(1-cos_grav), 28 sum(1-dot_deg^2) [ci<4]
#define NS 29
__global__ __launch_bounds__(256) void pass1_kernel(
    const float* __restrict__ pred_t, const float4* __restrict__ pred_q,
    const float* __restrict__ gt_t,   const float4* __restrict__ gt_q,
    const int* __restrict__ counts, const int* __restrict__ starts,
    float* __restrict__ segacc, int E)
{
    int wv = threadIdx.x >> 6;
    int lane = threadIdx.x & 63;
    int e = blockIdx.x * 4 + wv;
    if (e >= E) return;
    int start = starts[e];
    int ci = counts[e];
    bool small_c = (ci < 4);
    float4 q0p = pred_q[start];
    float4 q0g = gt_q[start];
    float4 q0pi = make_float4(-q0p.x, -q0p.y, -q0p.z, q0p.w);
    float4 q0gi = make_float4(-q0g.x, -q0g.y, -q0g.z, q0g.w);

    float acc[NS];
    #pragma unroll
    for (int k = 0; k < NS; ++k) acc[k] = 0.f;

    int iters = (ci + 63) >> 6;
    int i = lane;
    // prologue: load slot 0 (clamped index; counts >= 2 always)
    int m = start + min(i, ci - 1);
    float px = pred_t[3*m+0], py = pred_t[3*m+1], pz = pred_t[3*m+2];
    float gx = gt_t[3*m+0],  gy = gt_t[3*m+1],  gz = gt_t[3*m+2];
    float4 pq = pred_q[m];
    float4 gq = gt_q[m];

    for (int j = 0; ; ) {
        // ---- prefetch next slot before consuming current ----
        float npx = 0.f, npy = 0.f, npz = 0.f, ngx = 0.f, ngy = 0.f, ngz = 0.f;
        float4 npq = make_float4(0.f,0.f,0.f,0.f), ngq = npq;
        bool have_next = (j + 1 < iters);
        if (have_next) {
            int m2 = start + min(i + 64, ci - 1);
            npx = pred_t[3*m2+0]; npy = pred_t[3*m2+1]; npz = pred_t[3*m2+2];
            ngx = gt_t[3*m2+0];  ngy = gt_t[3*m2+1];  ngz = gt_t[3*m2+2];
            npq = pred_q[m2];
            ngq = gt_q[m2];
        }
        // ---- accumulate current (predicated on validity) ----
        if (i < ci) {
            acc[0] += px; acc[1] += py; acc[2] += pz;
            acc[3] += gx; acc[4] += gy; acc[5] += gz;
            acc[6] += px*px + py*py + pz*pz;
            acc[7] += gx*gx + gy*gy + gz*gz;
            acc[8]  += px*gx; acc[9]  += px*gy; acc[10] += px*gz;
            acc[11] += py*gx; acc[12] += py*gy; acc[13] += py*gz;
            acc[14] += pz*gx; acc[15] += pz*gy; acc[16] += pz*gz;

            // m_i = d(dot)/d(q_align_i), dot = <q_mul(q_align, pq), gq>
            float mx =  pq.w*gq.x - pq.z*gq.y + pq.y*gq.z - pq.x*gq.w;
            float my =  pq.z*gq.x + pq.w*gq.y - pq.x*gq.z - pq.y*gq.w;
            float mz = -pq.y*gq.x + pq.x*gq.y + pq.w*gq.z - pq.z*gq.w;
            float mw =  pq.x*gq.x + pq.y*gq.y + pq.z*gq.z + pq.w*gq.w;
            acc[17] += mx*mx; acc[18] += mx*my; acc[19] += mx*mz; acc[20] += mx*mw;
            acc[21] += my*my; acc[22] += my*mz; acc[23] += my*mw;
            acc[24] += mz*mz; acc[25] += mz*mw; acc[26] += mw*mw;

            // gravity: unit quats -> |pu|=|gu|=1, skip norm/div (R5-verified)
            float pu[3], gu[3];
            qinv_rot_up(pq, pu);
            qinv_rot_up(gq, gu);
            float cosv = pu[0]*gu[0] + pu[1]*gu[1] + pu[2]*gu[2];
            acc[27] += 1.f - cosv;

            if (small_c) {
                float4 aa = qmul4(q0pi, pq);
                float4 bb = qmul4(q0gi, gq);
                float dd = aa.x*bb.x + aa.y*bb.y + aa.z*bb.z + aa.w*bb.w;
                acc[28] += 1.f - dd*dd;
            }
        }
        if (!have_next) break;
        px = npx; py = npy; pz = npz;
        gx = ngx; gy = ngy; gz = ngz;
        pq = npq; gq = ngq;
        i += 64; ++j;
    }

    #pragma unroll
    for (int k = 0; k < NS; ++k) acc[k] = wave_sum(acc[k]);

    // lane k stores acc[k] -> one coalesced 116B store per segment
    float outv = 0.f;
    #pragma unroll
    for (int k = 0; k < NS; ++k)
        if (lane == k) outv = acc[k];
    if (lane < NS)
        segacc[(size_t)e*32 + lane] = outv;
}

// ---------------- kernel 3: per-LANE solve + loss reduction (fp32) -------------
__device__ void jacobi3f(float A[3][3], float V[3][3]) {
    V[0][0]=1.f; V[0][1]=0.f; V[0][2]=0.f;
    V[1][0]=0.f; V[1][1]=1.f; V[1][2]=0.f;
    V[2][0]=0.f; V[2][1]=0.f; V[2][2]=1.f;
    for (int sweep = 0; sweep < 6; ++sweep) {
        float off = A[0][1]*A[0][1] + A[0][2]*A[0][2] + A[1][2]*A[1][2];
        float dia = A[0][0]*A[0][0] + A[1][1]*A[1][1] + A[2][2]*A[2][2];
        if (off <= 1e-12f * (dia + 1e-30f)) break;
        for (int p = 0; p < 2; ++p) for (int q = p + 1; q < 3; ++q) {
            float apq = A[p][q];
            if (fabsf(apq) < 1e-30f) continue;
            float theta = (A[q][q] - A[p][p]) / (2.0f * apq);
            float t = ((theta >= 0.f) ? 1.f : -1.f) / (fabsf(theta) + sqrtf(theta*theta + 1.f));
            float cc = 1.f / sqrtf(t*t + 1.f);
            float ss = t * cc;
            float app = A[p][p], aqq = A[q][q];
            A[p][p] = app - t * apq;
            A[q][q] = aqq + t * apq;
            A[p][q] = 0.f; A[q][p] = 0.f;
            int r = 3 - p - q;
            float arp = A[r][p], arq = A[r][q];
            A[r][p] = cc*arp - ss*arq; A[p][r] = A[r][p];
            A[r][q] = ss*arp + cc*arq; A[q][r] = A[r][q];
            for (int i = 0; i < 3; ++i) {
                float vip = V[i][p], viq = V[i][q];
                V[i][p] = cc*vip - ss*viq;
                V[i][q] = ss*vip + cc*viq;
            }
        }
    }
}

__device__ void mat2quatf(const float R[3][3], float q[4]) {
    const float eps = 1e-12f;
    float tr = R[0][0] + R[1][1] + R[2][2];
    if (tr > 0.f) {
        float S = sqrtf(fmaxf(tr + 1.f, eps)) * 2.f;
        q[0] = (R[2][1]-R[1][2])/S; q[1] = (R[0][2]-R[2][0])/S;
        q[2] = (R[1][0]-R[0][1])/S; q[3] = 0.25f*S;
    } else if ((R[0][0] > R[1][1]) && (R[0][0] > R[2][2])) {
        float S = sqrtf(fmaxf(1.f + R[0][0] - R[1][1] - R[2][2], eps)) * 2.f;
        q[0] = 0.25f*S; q[1] = (R[0][1]+R[1][0])/S;
        q[2] = (R[0][2]+R[2][0])/S; q[3] = (R[2][1]-R[1][2])/S;
    } else if (R[1][1] > R[2][2]) {
        float S = sqrtf(fmaxf(1.f + R[1][1] - R[0][0] - R[2][2], eps)) * 2.f;
        q[0] = (R[0][1]+R[1][0])/S; q[1] = 0.25f*S;
        q[2] = (R[1][2]+R[2][1])/S; q[3] = (R[0][2]-R[2][0])/S;
    } else {
        float S = sqrtf(fmaxf(1.f + R[2][2] - R[0][0] - R[1][1], eps)) * 2.f;
        q[0] = (R[0][2]+R[2][0])/S; q[1] = (R[1][2]+R[2][1])/S;
        q[2] = 0.25f*S; q[3] = (R[1][0]-R[0][1])/S;
    }
}

__global__ __launch_bounds__(64) void finalize_kernel(
    const float* __restrict__ segacc, const int* __restrict__ counts,
    const int* __restrict__ starts, const float* __restrict__ pred_t,
    const float4* __restrict__ pred_q, const float4* __restrict__ gt_q,
    float* __restrict__ out, int E)
{
    int e = blockIdx.x * 64 + threadIdx.x;
    float v_trans = 0.f, v_rot = 0.f, v_grav = 0.f, v_leash = 0.f, v_scale = 0.f;
    if (e < E) {
        const float* A = segacc + (size_t)e * 32;
        int ci = counts[e];
        int start = starts[e];
        float c = (float)ci;
        float mu_p[3] = { A[0]/c, A[1]/c, A[2]/c };
        float mu_g[3] = { A[3]/c, A[4]/c, A[5]/c };
        float pp_c = A[6] - c*(mu_p[0]*mu_p[0]+mu_p[1]*mu_p[1]+mu_p[2]*mu_p[2]);
        float gg_c = A[7] - c*(mu_g[0]*mu_g[0]+mu_g[1]*mu_g[1]+mu_g[2]*mu_g[2]);
        float H[3][3];
        H[0][0]=A[8] -c*mu_p[0]*mu_g[0]; H[0][1]=A[9] -c*mu_p[0]*mu_g[1]; H[0][2]=A[10]-c*mu_p[0]*mu_g[2];
        H[1][0]=A[11]-c*mu_p[1]*mu_g[0]; H[1][1]=A[12]-c*mu_p[1]*mu_g[1]; H[1][2]=A[13]-c*mu_p[1]*mu_g[2];
        H[2][0]=A[14]-c*mu_p[2]*mu_g[0]; H[2][1]=A[15]-c*mu_p[2]*mu_g[1]; H[2][2]=A[16]-c*mu_p[2]*mu_g[2];
        float g_var = gg_c / (c - 1.0f);
        bool small_c = (ci < 4);
        bool deg = small_c || (g_var < 1e-4f);
        float trans, rot, scale = 0.f;
        if (deg) {
            float s28;
            if (small_c) {
                s28 = A[28];
            } else {
                // data-degenerate large segment (essentially never): re-stream
                float4 q0p = pred_q[start];
                float4 q0g = gt_q[start];
                float4 q0pi = make_float4(-q0p.x, -q0p.y, -q0p.z, q0p.w);
                float4 q0gi = make_float4(-q0g.x, -q0g.y, -q0g.z, q0g.w);
                float local = 0.f;
                for (int ii = 0; ii < ci; ++ii) {
                    float4 aa = qmul4(q0pi, pred_q[start + ii]);
                    float4 bb = qmul4(q0gi, gt_q[start + ii]);
                    float dd = aa.x*bb.x + aa.y*bb.y + aa.z*bb.z + aa.w*bb.w;
                    local += 1.f - dd*dd;
                }
                s28 = local;
            }
            float trH = H[0][0] + H[1][1] + H[2][2];
            trans = (pp_c - 2.f*trH + gg_c) / (c * 3.f);
            rot = s28 / c;
        } else {
            float B[3][3], V[3][3];
            for (int i = 0; i < 3; ++i)
                for (int j = 0; j < 3; ++j)
                    B[i][j] = H[0][i]*H[0][j] + H[1][i]*H[1][j] + H[2][i]*H[2][j];
            jacobi3f(B, V);
            float lam[3] = { B[0][0], B[1][1], B[2][2] };
            int idx[3] = {0, 1, 2};
            if (lam[idx[0]] < lam[idx[1]]) { int t = idx[0]; idx[0] = idx[1]; idx[1] = t; }
            if (lam[idx[0]] < lam[idx[2]]) { int t = idx[0]; idx[0] = idx[2]; idx[2] = t; }
            if (lam[idx[1]] < lam[idx[2]]) { int t = idx[1]; idx[1] = idx[2]; idx[2] = t; }
            float v1[3], v2[3], v3[3];
            for (int i = 0; i < 3; ++i) { v1[i] = V[i][idx[0]]; v2[i] = V[i][idx[1]]; v3[i] = V[i][idx[2]]; }
            float detV = v1[0]*(v2[1]*v3[2]-v2[2]*v3[1])
                       - v1[1]*(v2[0]*v3[2]-v2[2]*v3[0])
                       + v1[2]*(v2[0]*v3[1]-v2[1]*v3[0]);
            float sgnV = (detV < 0.f) ? -1.f : 1.f;
            float u1[3], u2[3], u3[3];
            for (int i = 0; i < 3; ++i) u1[i] = H[i][0]*v1[0] + H[i][1]*v1[1] + H[i][2]*v1[2];
            float n1 = fmaxf(sqrtf(u1[0]*u1[0]+u1[1]*u1[1]+u1[2]*u1[2]), 1e-30f);
            for (int i = 0; i < 3; ++i) u1[i] /= n1;
            for (int i = 0; i < 3; ++i) u2[i] = H[i][0]*v2[0] + H[i][1]*v2[1] + H[i][2]*v2[2];
            float d12 = u1[0]*u2[0]+u1[1]*u2[1]+u1[2]*u2[2];
            for (int i = 0; i < 3; ++i) u2[i] -= d12*u1[i];
            float n2 = fmaxf(sqrtf(u2[0]*u2[0]+u2[1]*u2[1]+u2[2]*u2[2]), 1e-30f);
            for (int i = 0; i < 3; ++i) u2[i] /= n2;
            u3[0] = u1[1]*u2[2] - u1[2]*u2[1];
            u3[1] = u1[2]*u2[0] - u1[0]*u2[2];
            u3[2] = u1[0]*u2[1] - u1[1]*u2[0];
            // R = v1 u1^T + v2 u2^T + sgnV*v3 u3^T (== ref V diag(1,1,sgn) U^T)
            float R[3][3];
            for (int i = 0; i < 3; ++i)
                for (int k = 0; k < 3; ++k)
                    R[i][k] = v1[i]*u1[k] + v2[i]*u2[k] + sgnV*v3[i]*u3[k];
            float nom = 0.f;
            for (int k = 0; k < 3; ++k)
                for (int j = 0; j < 3; ++j)
                    nom += R[k][j] * H[j][k];
            float denom = pp_c;
            float s = 1.f;
            if (denom > 1e-6f) {
                s = nom / fmaxf(denom, 1e-6f);
                s = fminf(fmaxf(s, 1e-3f), 1e3f);
            }
            trans = (s*s*denom - 2.f*s*nom + gg_c) / (c * 3.f);
            float ls = logf(fabsf(s) + 1e-6f);
            scale = ls * ls;
            float q[4];
            mat2quatf(R, q);
            float quad = q[0]*q[0]*A[17] + q[1]*q[1]*A[21] + q[2]*q[2]*A[24] + q[3]*q[3]*A[26]
                + 2.f*(q[0]*q[1]*A[18] + q[0]*q[2]*A[19] + q[0]*q[3]*A[20]
                     + q[1]*q[2]*A[22] + q[1]*q[3]*A[23] + q[2]*q[3]*A[25]);
            rot = (c - quad) / c;
        }
        float grav = A[27] / c;
        float tx = pred_t[3*start+0], ty = pred_t[3*start+1], tz = pred_t[3*start+2];
        float mag = sqrtf(tx*tx + ty*ty + tz*tz);
        float ml = fmaxf(mag - 15.f, 0.f);
        float Ed = (float)E;
        v_trans = trans / Ed;
        v_rot   = rot / Ed;
        v_grav  = grav / Ed;
        v_leash = (ml * ml) / Ed;
        v_scale = scale / Ed;
    }
    // wave-level reduce, 5 atomics per block (64 blocks -> 320 total).
    // Round-1 lesson: never scale same-line atomics with E (20K atomics on one
    // 32B line serialized at a single TCC channel and cost ~40us).
    float vals[5] = { v_trans, v_rot, v_grav, v_leash, v_scale };
    #pragma unroll
    for (int k = 0; k < 5; ++k) {
        float v = wave_sum(vals[k]);
        if (threadIdx.x == 0) atomicAdd(out + k, v);
    }
}

extern "C" void kernel_launch(void* const* d_in, const int* in_sizes, int n_in,
                              void* d_out, int out_size, void* d_ws, size_t ws_size,
                              hipStream_t stream) {
    const float*  pred_t = (const float*)d_in[0];
    const float4* pred_q = (const float4*)d_in[1];
    const float*  gt_t   = (const float*)d_in[2];
    const float4* gt_q   = (const float4*)d_in[3];
    const int*    counts = (const int*)d_in[4];
    int E = in_sizes[4];

    int* starts = (int*)d_ws;
    size_t off = ((size_t)E * sizeof(int) + 255) & ~(size_t)255;
    float* segacc = (float*)((char*)d_ws + off);

    scan_kernel<<<1, 1024, 0, stream>>>(counts, starts, (float*)d_out, E);
    pass1_kernel<<<(E + 3) / 4, 256, 0, stream>>>(pred_t, pred_q, gt_t, gt_q,
                                                  counts, starts, segacc, E);
    finalize_kernel<<<(E + 63) / 64, 64, 0, stream>>>(segacc, counts, starts, pred_t,
                                                      pred_q, gt_q, (float*)d_out, E);
}